// Round 2
// 637.038 us; speedup vs baseline: 1.0286x; 1.0286x over previous
//
#include <hip/hip_runtime.h>
#include <hip/hip_bf16.h>
#include <math.h>

#define Bn 2
#define Hn 56
#define Wn 56
#define Cn 256
#define Nh 8
#define Dh 32
#define Fn 1024
#define Ln (Hn*Wn)          // 3136
#define Mrows (Bn*Ln)       // 6272
#define SCALING_K 0.17677669529663687f   // 32^-0.5

typedef __attribute__((ext_vector_type(4))) float f32x4;
typedef __attribute__((ext_vector_type(8))) short s16x8;
typedef unsigned short ushort_t;

__device__ __forceinline__ ushort_t f2bf(float f) {
    __hip_bfloat16 h = __float2bfloat16(f);
    return *reinterpret_cast<ushort_t*>(&h);
}

// ---------------- weight transpose: fp32 [K][N] -> bf16 [N][K], LDS-tiled ----------------
__global__ __launch_bounds__(256) void transpose_w(
    const float* __restrict__ wq, const float* __restrict__ wk, const float* __restrict__ wv,
    const float* __restrict__ wo, const float* __restrict__ w1, const float* __restrict__ w2,
    ushort_t* __restrict__ wqkvT, ushort_t* __restrict__ woT,
    ushort_t* __restrict__ w1T, ushort_t* __restrict__ w2T)
{
    int z = blockIdx.z;
    const float* src; ushort_t* dst; int K, N; float scale = 1.f;
    switch (z) {
      case 0: src=wq; dst=wqkvT;           K=256;  N=256;  break;
      case 1: src=wk; dst=wqkvT+256*256;   K=256;  N=256;  scale=SCALING_K; break;
      case 2: src=wv; dst=wqkvT+512*256;   K=256;  N=256;  break;
      case 3: src=wo; dst=woT;             K=256;  N=256;  break;
      case 4: src=w1; dst=w1T;             K=256;  N=1024; break;
      default: src=w2; dst=w2T;            K=1024; N=256;  break;
    }
    int n0 = blockIdx.x << 5, k0 = blockIdx.y << 5;
    if (n0 >= N || k0 >= K) return;
    __shared__ float tile[32][33];
    int tx = threadIdx.x & 31, ty = threadIdx.x >> 5;   // 32 x 8
    #pragma unroll
    for (int r = 0; r < 4; ++r)
        tile[ty + 8*r][tx] = src[(size_t)(k0 + ty + 8*r)*N + n0 + tx] * scale;
    __syncthreads();
    #pragma unroll
    for (int r = 0; r < 4; ++r)
        dst[(size_t)(n0 + ty + 8*r)*K + k0 + tx] = f2bf(tile[tx][ty + 8*r]);
}

__global__ void prep_bias(const float* __restrict__ bq, const float* __restrict__ bk,
                          const float* __restrict__ bv, float* __restrict__ bqkv)
{
    int i = blockIdx.x*256 + threadIdx.x;
    if (i < 768)
        bqkv[i] = (i < 256) ? bq[i] : (i < 512 ? bk[i-256]*SCALING_K : bv[i-512]);
}

// ---------------- pos dwconv3x3 + residual; fused LN1-apply -> bf16 A ----------------
// block: 16 pixels (4 pixel-quads) x 64 channel-groups; one wave per pixel-quad.
// After the wave shfl reduce every lane holds the full-row sums, so LN is applied
// here ONCE instead of per-column-tile inside the QKV GEMM.
__global__ __launch_bounds__(256) void dwconv_ln(
    const float* __restrict__ x, const float* __restrict__ wgt, const float* __restrict__ bias,
    const float* __restrict__ lng, const float* __restrict__ lnb,
    float* __restrict__ out, ushort_t* __restrict__ ybf)
{
    int t = threadIdx.x;
    int cg = t & 63;
    int g = blockIdx.x*4 + (t >> 6);       // pixel-quad index
    int w0 = (g % 14) << 2;
    int hr = g / 14;                        // b*Hn + h
    int h = hr % Hn;
    int c = cg << 2;
    float4 wv9[9];
    #pragma unroll
    for (int i = 0; i < 9; ++i) wv9[i] = *(const float4*)&wgt[i*Cn + c];
    float4 bias4 = *(const float4*)&bias[c];
    float4 acc[4] = {bias4, bias4, bias4, bias4};
    const float* base = x + (size_t)(hr - h)*Wn*Cn + c;
    #pragma unroll
    for (int dh = 0; dh < 3; ++dh) {
        int hh = h + dh - 1;
        if (hh < 0 || hh >= Hn) continue;
        const float* rowp = base + (size_t)hh*Wn*Cn;
        float4 xv[6];
        #pragma unroll
        for (int j = 0; j < 6; ++j) {
            int wc = w0 - 1 + j;
            xv[j] = (wc >= 0 && wc < Wn) ? *(const float4*)&rowp[(size_t)wc*Cn]
                                         : make_float4(0.f,0.f,0.f,0.f);
        }
        #pragma unroll
        for (int dw = 0; dw < 3; ++dw) {
            float4 wv = wv9[dh*3 + dw];
            #pragma unroll
            for (int p = 0; p < 4; ++p) {
                acc[p].x += xv[p+dw].x*wv.x; acc[p].y += xv[p+dw].y*wv.y;
                acc[p].z += xv[p+dw].z*wv.z; acc[p].w += xv[p+dw].w*wv.w;
            }
        }
        if (dh == 1) {
            #pragma unroll
            for (int p = 0; p < 4; ++p) {
                acc[p].x += xv[p+1].x; acc[p].y += xv[p+1].y;
                acc[p].z += xv[p+1].z; acc[p].w += xv[p+1].w;
            }
        }
    }
    float s[4], q[4];
    #pragma unroll
    for (int p = 0; p < 4; ++p) {
        s[p] = acc[p].x + acc[p].y + acc[p].z + acc[p].w;
        q[p] = acc[p].x*acc[p].x + acc[p].y*acc[p].y + acc[p].z*acc[p].z + acc[p].w*acc[p].w;
    }
    #pragma unroll
    for (int m = 1; m < 64; m <<= 1) {
        #pragma unroll
        for (int p = 0; p < 4; ++p) {
            s[p] += __shfl_xor(s[p], m);
            q[p] += __shfl_xor(q[p], m);
        }
    }
    float4 g4 = *(const float4*)&lng[c];
    float4 b4 = *(const float4*)&lnb[c];
    size_t pixbase = (size_t)hr*Wn + w0;
    #pragma unroll
    for (int p = 0; p < 4; ++p) {
        *(float4*)&out[(pixbase + p)*Cn + c] = acc[p];
        float mean = s[p] * (1.0f/Cn);
        float rstd = rsqrtf(q[p] * (1.0f/Cn) - mean*mean + 1e-6f);
        ushort_t o[4] = {
            f2bf((acc[p].x - mean)*rstd*g4.x + b4.x),
            f2bf((acc[p].y - mean)*rstd*g4.y + b4.y),
            f2bf((acc[p].z - mean)*rstd*g4.z + b4.z),
            f2bf((acc[p].w - mean)*rstd*g4.w + b4.w)
        };
        *(uint2*)&ybf[(pixbase + p)*Cn + c] = *(uint2*)o;
    }
}

// ---------------- generic dwconv, 4 pixels/thread, optional bf16 out ----------------
template<int KS, int OBF>
__global__ __launch_bounds__(256) void dwconv4(
    const float* __restrict__ in, const float* __restrict__ wgt, const float* __restrict__ bias,
    void* __restrict__ outv, int C, int inld, int addin)
{
    constexpr int PAD = KS/2;
    int t = threadIdx.x;
    int cgs = C >> 2;
    int qpb = 256 / cgs;
    int cg = t % cgs;
    int g = blockIdx.x*qpb + t/cgs;
    int w0 = (g % 14) << 2;
    int hr = g / 14;
    int h = hr % Hn;
    int c = cg << 2;
    float4 bias4 = *(const float4*)&bias[c];
    float4 acc[4] = {bias4, bias4, bias4, bias4};
    const float* base = in + (size_t)(hr - h)*Wn*inld + c;
    #pragma unroll
    for (int dh = 0; dh < KS; ++dh) {
        int hh = h + dh - PAD;
        if (hh < 0 || hh >= Hn) continue;
        const float* rowp = base + (size_t)hh*Wn*inld;
        float4 xv[KS+3];
        #pragma unroll
        for (int j = 0; j < KS+3; ++j) {
            int wc = w0 - PAD + j;
            xv[j] = (wc >= 0 && wc < Wn) ? *(const float4*)&rowp[(size_t)wc*inld]
                                         : make_float4(0.f,0.f,0.f,0.f);
        }
        #pragma unroll
        for (int dw = 0; dw < KS; ++dw) {
            float4 wv = *(const float4*)&wgt[(dh*KS + dw)*C + c];
            #pragma unroll
            for (int p = 0; p < 4; ++p) {
                acc[p].x += xv[p+dw].x*wv.x; acc[p].y += xv[p+dw].y*wv.y;
                acc[p].z += xv[p+dw].z*wv.z; acc[p].w += xv[p+dw].w*wv.w;
            }
        }
        if (addin && dh == PAD) {
            #pragma unroll
            for (int p = 0; p < 4; ++p) {
                acc[p].x += xv[p+PAD].x; acc[p].y += xv[p+PAD].y;
                acc[p].z += xv[p+PAD].z; acc[p].w += xv[p+PAD].w;
            }
        }
    }
    size_t pixbase = (size_t)hr*Wn + w0;
    if (OBF) {
        ushort_t* outb = (ushort_t*)outv;
        #pragma unroll
        for (int p = 0; p < 4; ++p) {
            ushort_t tmp[4] = { f2bf(acc[p].x), f2bf(acc[p].y), f2bf(acc[p].z), f2bf(acc[p].w) };
            *(uint2*)&outb[(pixbase + p)*C + c] = *(uint2*)tmp;
        }
    } else {
        float* outf = (float*)outv;
        #pragma unroll
        for (int p = 0; p < 4; ++p)
            *(float4*)&outf[(pixbase + p)*C + c] = acc[p];
    }
}

// ---------------- LN2: stats + apply + bf16 cast, one wave per row ----------------
__global__ __launch_bounds__(256) void ln_apply(
    const float* __restrict__ in, const float* __restrict__ g, const float* __restrict__ b,
    ushort_t* __restrict__ out)
{
    int t = threadIdx.x;
    int lane = t & 63;
    int row = blockIdx.x*4 + (t >> 6);
    int c = lane << 2;
    float4 v = *(const float4*)&in[(size_t)row*Cn + c];
    float s1 = v.x + v.y + v.z + v.w;
    float s2 = v.x*v.x + v.y*v.y + v.z*v.z + v.w*v.w;
    #pragma unroll
    for (int m = 1; m < 64; m <<= 1) {
        s1 += __shfl_xor(s1, m);
        s2 += __shfl_xor(s2, m);
    }
    float mean = s1 * (1.0f/Cn);
    float rstd = rsqrtf(s2 * (1.0f/Cn) - mean*mean + 1e-6f);
    float4 g4 = *(const float4*)&g[c];
    float4 b4 = *(const float4*)&b[c];
    ushort_t o[4] = {
        f2bf((v.x - mean)*rstd*g4.x + b4.x),
        f2bf((v.y - mean)*rstd*g4.y + b4.y),
        f2bf((v.z - mean)*rstd*g4.z + b4.z),
        f2bf((v.w - mean)*rstd*g4.w + b4.w)
    };
    *(uint2*)&out[(size_t)row*Cn + c] = *(uint2*)o;
}

// ---------------- bf16 MFMA GEMM, bf16 A always; bias/gelu/resid epilogue ----------------
// tile 64(M)x64(N), BK=32, 256 thr / 4 waves. grid.x = N/64, grid.y = M/64.
__global__ __launch_bounds__(256) void gemm_bf16(
    const ushort_t* __restrict__ A, int lda,
    const ushort_t* __restrict__ BT, const float* __restrict__ bias,
    const float* __restrict__ resid, float* __restrict__ out, int ldo,
    int K, int gelu_flag)
{
    __shared__ __align__(16) ushort_t As[64][40];
    __shared__ __align__(16) ushort_t Bs[64][40];
    int t = threadIdx.x;
    int wid = t >> 6, lane = t & 63, l16 = lane & 15, quad = lane >> 4;
    int n0 = blockIdx.x << 6, m0 = blockIdx.y << 6;
    int srow = t >> 2, skc = (t & 3) << 3;
    f32x4 acc[4] = {{0,0,0,0},{0,0,0,0},{0,0,0,0},{0,0,0,0}};
    for (int k0 = 0; k0 < K; k0 += 32) {
        uint4 av4 = *(const uint4*)&A[(size_t)(m0+srow)*lda + k0 + skc];
        uint4 bv4 = *(const uint4*)&BT[(size_t)(n0+srow)*K + k0 + skc];
        __syncthreads();
        *(uint4*)&As[srow][skc] = av4;
        *(uint4*)&Bs[srow][skc] = bv4;
        __syncthreads();
        s16x8 af = *(const s16x8*)&As[wid*16 + l16][quad*8];
        #pragma unroll
        for (int j = 0; j < 4; ++j) {
            s16x8 bf = *(const s16x8*)&Bs[j*16 + l16][quad*8];
            acc[j] = __builtin_amdgcn_mfma_f32_16x16x32_bf16(af, bf, acc[j], 0, 0, 0);
        }
    }
    #pragma unroll
    for (int j = 0; j < 4; ++j) {
        int col = n0 + j*16 + l16;
        float bv = bias[col];
        #pragma unroll
        for (int r = 0; r < 4; ++r) {
            int row = m0 + wid*16 + quad*4 + r;
            float v = acc[j][r] + bv;
            if (gelu_flag) v = 0.5f * v * (1.0f + erff(v * 0.70710678118654752f));
            size_t off = (size_t)row*ldo + col;
            if (resid) v += resid[off];
            out[off] = v;
        }
    }
}

// ---------------- pack: theta-shift + cast to bf16, head-major; V transposed ----------------
__global__ __launch_bounds__(256) void pack_qkv(
    const float* __restrict__ qkv,
    const float* __restrict__ sp, const float* __restrict__ cp,
    ushort_t* __restrict__ qb, ushort_t* __restrict__ kb, ushort_t* __restrict__ vbT)
{
    __shared__ __align__(16) ushort_t Vl[64][40];
    int t = threadIdx.x;
    int l0 = blockIdx.x << 6;
    int n = blockIdx.y;
    int b = blockIdx.z;
    {
        int ll = t >> 2, dc = (t & 3) << 3;
        int l = l0 + ll;
        size_t gbase = ((size_t)(b*Ln + l))*768 + n*Dh + dc;
        float qx[8], kx[8], vx[8], sv[8], cv[8];
        *(float4*)&qx[0] = *(const float4*)&qkv[gbase];
        *(float4*)&qx[4] = *(const float4*)&qkv[gbase+4];
        *(float4*)&kx[0] = *(const float4*)&qkv[gbase+256];
        *(float4*)&kx[4] = *(const float4*)&qkv[gbase+260];
        *(float4*)&vx[0] = *(const float4*)&qkv[gbase+512];
        *(float4*)&vx[4] = *(const float4*)&qkv[gbase+516];
        size_t scb = (size_t)l*Dh + dc;
        *(float4*)&sv[0] = *(const float4*)&sp[scb];
        *(float4*)&sv[4] = *(const float4*)&sp[scb+4];
        *(float4*)&cv[0] = *(const float4*)&cp[scb];
        *(float4*)&cv[4] = *(const float4*)&cp[scb+4];
        ushort_t qo[8], ko[8], vo[8];
        #pragma unroll
        for (int j = 0; j < 8; j += 2) {
            float q0 = qx[j]*cv[j] - qx[j+1]*sv[j];
            float q1 = qx[j+1]*cv[j+1] + qx[j]*sv[j+1];
            float k0 = kx[j]*cv[j] - kx[j+1]*sv[j];
            float k1 = kx[j+1]*cv[j+1] + kx[j]*sv[j+1];
            qo[j] = f2bf(q0); qo[j+1] = f2bf(q1);
            ko[j] = f2bf(k0); ko[j+1] = f2bf(k1);
            vo[j] = f2bf(vx[j]); vo[j+1] = f2bf(vx[j+1]);
        }
        size_t hbase = ((size_t)((b*Nh + n)*Ln + l))*Dh + dc;
        *(uint4*)&qb[hbase] = *(uint4*)qo;
        *(uint4*)&kb[hbase] = *(uint4*)ko;
        *(uint4*)&Vl[ll][dc] = *(uint4*)vo;
    }
    __syncthreads();
    {
        int d = t >> 3, lc = (t & 7) << 3;
        ushort_t tmp[8];
        #pragma unroll
        for (int i = 0; i < 8; ++i) tmp[i] = Vl[lc + i][d];
        size_t tbase = ((size_t)((b*Nh + n)*Dh + d))*Ln + l0 + lc;
        *(uint4*)&vbT[tbase] = *(uint4*)tmp;
    }
}

// ---------------- MFMA flash attention, batch-merged, register-prefetch pipeline ----------------
// Epilogue fuses +lepe and emits bf16 (the A operand of the wo GEMM).
__global__ __launch_bounds__(512) void flash_mfma(
    const ushort_t* __restrict__ qb, const ushort_t* __restrict__ kb,
    const ushort_t* __restrict__ vbT, const float* __restrict__ mask,
    const float* __restrict__ lepe, ushort_t* __restrict__ out)
{
    __shared__ __align__(16) ushort_t Kt[2][64][40];   // [b][key][d]
    __shared__ __align__(16) ushort_t Vt[2][32][72];   // [b][d][key]
    __shared__ __align__(16) ushort_t Ps[8][16][72];   // per-wave P tile
    int t = threadIdx.x;
    int wid = t >> 6, lane = t & 63, l16 = lane & 15, quad = lane >> 4;
    int bb = wid & 1, wq16 = wid >> 1;
    int l0 = blockIdx.x << 6;
    int n = blockIdx.y;

    const ushort_t* qbp = qb + ((size_t)(bb*Nh + n))*Ln*Dh;
    s16x8 qfrag = *(const s16x8*)(qbp + (size_t)(l0 + wq16*16 + l16)*Dh + quad*8);
    const float* mbase = mask + (size_t)n*Ln*Ln + (size_t)(l0 + wq16*16 + quad*4)*Ln;

    int sb   = t >> 8;
    int krow = (t >> 2) & 63, kkc = (t & 3) << 3;
    int vrow = (t >> 3) & 31, vkc = (t & 7) << 3;
    const ushort_t* kst = kb  + ((size_t)(sb*Nh + n))*Ln*Dh;
    const ushort_t* vst = vbT + ((size_t)((sb*Nh + n)*Dh + vrow))*Ln;

    f32x4 O0 = {0.f,0.f,0.f,0.f}, O1 = {0.f,0.f,0.f,0.f};
    float m_[4], l_[4];
    #pragma unroll
    for (int r = 0; r < 4; ++r) { m_[r] = -INFINITY; l_[r] = 0.f; }

    // prologue prefetch for tile 0
    uint4 kreg = *(const uint4*)(kst + (size_t)krow*Dh + kkc);
    uint4 vreg = *(const uint4*)(vst + vkc);
    f32x4 c0, c1, c2, c3;
    #pragma unroll
    for (int r = 0; r < 4; ++r) {
        const float* mr = mbase + (size_t)r*Ln + l16;
        c0[r] = mr[0]; c1[r] = mr[16]; c2[r] = mr[32]; c3[r] = mr[48];
    }

    for (int m0 = 0; m0 < Ln; m0 += 64) {
        __syncthreads();
        *(uint4*)&Kt[sb][krow][kkc] = kreg;
        *(uint4*)&Vt[sb][vrow][vkc] = vreg;
        __syncthreads();

        // prefetch next tile (in flight across this iteration's compute)
        int m1 = m0 + 64;
        uint4 krn = kreg, vrn = vreg;
        f32x4 d0 = c0, d1 = c1, d2 = c2, d3 = c3;
        if (m1 < Ln) {
            krn = *(const uint4*)(kst + (size_t)(m1 + krow)*Dh + kkc);
            vrn = *(const uint4*)(vst + m1 + vkc);
            #pragma unroll
            for (int r = 0; r < 4; ++r) {
                const float* mr = mbase + (size_t)r*Ln + m1 + l16;
                d0[r] = mr[0]; d1[r] = mr[16]; d2[r] = mr[32]; d3[r] = mr[48];
            }
        }

        f32x4 S[4];
        {
            s16x8 kf0 = *(const s16x8*)&Kt[bb][ 0 + l16][quad*8];
            s16x8 kf1 = *(const s16x8*)&Kt[bb][16 + l16][quad*8];
            s16x8 kf2 = *(const s16x8*)&Kt[bb][32 + l16][quad*8];
            s16x8 kf3 = *(const s16x8*)&Kt[bb][48 + l16][quad*8];
            S[0] = __builtin_amdgcn_mfma_f32_16x16x32_bf16(qfrag, kf0, c0, 0, 0, 0);
            S[1] = __builtin_amdgcn_mfma_f32_16x16x32_bf16(qfrag, kf1, c1, 0, 0, 0);
            S[2] = __builtin_amdgcn_mfma_f32_16x16x32_bf16(qfrag, kf2, c2, 0, 0, 0);
            S[3] = __builtin_amdgcn_mfma_f32_16x16x32_bf16(qfrag, kf3, c3, 0, 0, 0);
        }
        #pragma unroll
        for (int r = 0; r < 4; ++r) {
            float tm = fmaxf(fmaxf(S[0][r], S[1][r]), fmaxf(S[2][r], S[3][r]));
            tm = fmaxf(tm, __shfl_xor(tm, 1));
            tm = fmaxf(tm, __shfl_xor(tm, 2));
            tm = fmaxf(tm, __shfl_xor(tm, 4));
            tm = fmaxf(tm, __shfl_xor(tm, 8));
            float nm = fmaxf(m_[r], tm);
            float al = __expf(m_[r] - nm);
            m_[r] = nm;
            float p0 = __expf(S[0][r] - nm);
            float p1 = __expf(S[1][r] - nm);
            float p2 = __expf(S[2][r] - nm);
            float p3 = __expf(S[3][r] - nm);
            float ps = p0 + p1 + p2 + p3;
            ps += __shfl_xor(ps, 1); ps += __shfl_xor(ps, 2);
            ps += __shfl_xor(ps, 4); ps += __shfl_xor(ps, 8);
            l_[r] = l_[r]*al + ps;
            O0[r] *= al; O1[r] *= al;
            int rr = quad*4 + r;
            Ps[wid][rr][ 0 + l16] = f2bf(p0);
            Ps[wid][rr][16 + l16] = f2bf(p1);
            Ps[wid][rr][32 + l16] = f2bf(p2);
            Ps[wid][rr][48 + l16] = f2bf(p3);
        }
        #pragma unroll
        for (int kc = 0; kc < 2; ++kc) {
            s16x8 pf  = *(const s16x8*)&Ps[wid][l16][kc*32 + quad*8];
            s16x8 vf0 = *(const s16x8*)&Vt[bb][ 0 + l16][kc*32 + quad*8];
            s16x8 vf1 = *(const s16x8*)&Vt[bb][16 + l16][kc*32 + quad*8];
            O0 = __builtin_amdgcn_mfma_f32_16x16x32_bf16(pf, vf0, O0, 0, 0, 0);
            O1 = __builtin_amdgcn_mfma_f32_16x16x32_bf16(pf, vf1, O1, 0, 0, 0);
        }
        kreg = krn; vreg = vrn;
        c0 = d0; c1 = d1; c2 = d2; c3 = d3;
    }
    #pragma unroll
    for (int r = 0; r < 4; ++r) {
        float inv = 1.0f / l_[r];
        size_t row = (size_t)(bb*Ln + l0 + wq16*16 + quad*4 + r)*Cn + n*Dh;
        out[row + l16]      = f2bf(O0[r] * inv + lepe[row + l16]);
        out[row + 16 + l16] = f2bf(O1[r] * inv + lepe[row + 16 + l16]);
    }
}

extern "C" void kernel_launch(void* const* d_in, const int* in_sizes, int n_in,
                              void* d_out, int out_size, void* d_ws, size_t ws_size,
                              hipStream_t stream) {
    const float* x     = (const float*)d_in[0];
    const float* sinp  = (const float*)d_in[1];
    const float* cosp  = (const float*)d_in[2];
    const float* mask  = (const float*)d_in[3];
    const float* pos_w = (const float*)d_in[4];
    const float* pos_b = (const float*)d_in[5];
    const float* ln1_g = (const float*)d_in[6];
    const float* ln1_b = (const float*)d_in[7];
    const float* wq = (const float*)d_in[8];
    const float* bq = (const float*)d_in[9];
    const float* wk = (const float*)d_in[10];
    const float* bk = (const float*)d_in[11];
    const float* wv = (const float*)d_in[12];
    const float* bv = (const float*)d_in[13];
    const float* lepe_w = (const float*)d_in[14];
    const float* lepe_b = (const float*)d_in[15];
    const float* wo = (const float*)d_in[16];
    const float* bo = (const float*)d_in[17];
    const float* ln2_g = (const float*)d_in[18];
    const float* ln2_b = (const float*)d_in[19];
    const float* w1 = (const float*)d_in[20];
    const float* b1 = (const float*)d_in[21];
    const float* ffn_w = (const float*)d_in[22];
    const float* ffn_b = (const float*)d_in[23];
    const float* w2 = (const float*)d_in[24];
    const float* b2 = (const float*)d_in[25];

    float* ws = (float*)d_ws;
    const size_t MC = (size_t)Mrows*Cn;   // 1,605,632 floats
    const size_t HC = MC/2;               // 802,816 floats
    // Compact layout with lifetime-based reuse (peak ~72 MB, < round-0's 95 MB):
    //   [0,1MC)      xbuf   fp32 residual (live steps 1-6)
    //   [1,2MC)      x2     fp32 residual (live steps 6-10)
    //   [2,3MC)      lepe   fp32 (steps 4-5)
    //   [3,3.5MC)    ybf    bf16 LN1(xbuf) (steps 1-2)
    //   [3.5,4MC)    attbf  bf16 att+lepe (steps 5-6)
    //   [4,4.5MC)    zbf    bf16 LN2(x2) (steps 7-8)
    //   [4.5,7.5MC)  qkv    fp32 (steps 2-4)   } z1 [4.5,8.5MC) reuses these
    //   [7.5,8MC)    qb, [8,8.5MC) kb          } (qkv/qb/kb dead before step 8)
    //   [8.5,9MC)    vbT    (steps 3-5)
    //   [9,11MC)     z2bf   bf16 [M][1024] (steps 9-10)
    //   [11MC, +394k) weights
    float* xbuf = ws;
    float* x2   = ws + MC;
    float* lepe = ws + 2*MC;
    ushort_t* ybf   = (ushort_t*)(ws + 3*MC);
    ushort_t* attbf = (ushort_t*)(ws + 3*MC + HC);
    ushort_t* zbf   = (ushort_t*)(ws + 4*MC);
    float* qkv = ws + 4*MC + HC;
    ushort_t* qb  = (ushort_t*)(ws + 7*MC + HC);
    ushort_t* kb  = (ushort_t*)(ws + 8*MC);
    ushort_t* vbT = (ushort_t*)(ws + 8*MC + HC);
    float* z1 = ws + 4*MC + HC;               // reuses qkv/qb/kb region
    ushort_t* z2bf = (ushort_t*)(ws + 9*MC);  // 2MC floats
    float* wtb = ws + 11*MC;
    ushort_t* wqkvT = (ushort_t*)wtb;                 // 196608 us = 98304 f
    ushort_t* woT   = (ushort_t*)(wtb + 98304);       // 65536 us = 32768 f
    ushort_t* w1T   = (ushort_t*)(wtb + 131072);      // 262144 us = 131072 f
    ushort_t* w2T   = (ushort_t*)(wtb + 262144);      // 262144 us = 131072 f
    float*    bqkv  = wtb + 393216;                   // 768 f
    float* outp = (float*)d_out;

    // 0. weight prep
    transpose_w<<<dim3(32,32,6), 256, 0, stream>>>(wq,wk,wv,wo,w1,w2, wqkvT,woT,w1T,w2T);
    prep_bias<<<3, 256, 0, stream>>>(bq,bk,bv,bqkv);
    // 1. xbuf = x + dwconv3x3(x); ybf = bf16(LN1(xbuf)) fused
    dwconv_ln<<<Mrows/16, 256, 0, stream>>>(x, pos_w, pos_b, ln1_g, ln1_b, xbuf, ybf);
    // 2. qkv = ybf @ [wq|wk*s|wv] + [bq|bk*s|bv]
    gemm_bf16<<<dim3(12, Mrows/64), 256, 0, stream>>>(ybf, Cn,
        wqkvT, bqkv, nullptr, qkv, 768, Cn, 0);
    // 3. pack: theta shift + bf16 head-major + V transpose
    pack_qkv<<<dim3(Ln/64, Nh, Bn), 256, 0, stream>>>(qkv, sinp, cosp, qb, kb, vbT);
    // 4. lepe = dwconv5x5(v)
    dwconv4<5,0><<<Mrows/16, 256, 0, stream>>>(qkv+512, lepe_w, lepe_b, lepe, Cn, 768, 0);
    // 5. attention; epilogue adds lepe and emits bf16
    flash_mfma<<<dim3(Ln/64, Nh), 512, 0, stream>>>(qb, kb, vbT, mask, lepe, attbf);
    // 6. x2 = xbuf + attbf @ wo + bo
    gemm_bf16<<<dim3(4, Mrows/64), 256, 0, stream>>>(attbf, Cn,
        woT, bo, xbuf, x2, Cn, Cn, 0);
    // 7. zbf = bf16(LN2(x2))
    ln_apply<<<Mrows/4, 256, 0, stream>>>(x2, ln2_g, ln2_b, zbf);
    // 8. z1 = gelu(zbf @ w1 + b1)
    gemm_bf16<<<dim3(16, Mrows/64), 256, 0, stream>>>(zbf, Cn,
        w1T, b1, nullptr, z1, Fn, Cn, 1);
    // 9. z2 = z1 + dwconv3x3(z1), stored bf16
    dwconv4<3,1><<<Mrows/4, 256, 0, stream>>>(z1, ffn_w, ffn_b, z2bf, Fn, Fn, 1);
    // 10. out = x2 + z2 @ w2 + b2
    gemm_bf16<<<dim3(4, Mrows/64), 256, 0, stream>>>(z2bf, Fn,
        w2T, b2, x2, outp, Cn, Fn, 0);
}

// Round 3
// 629.151 us; speedup vs baseline: 1.0415x; 1.0125x over previous
//
#include <hip/hip_runtime.h>
#include <hip/hip_bf16.h>
#include <math.h>

#define Bn 2
#define Hn 56
#define Wn 56
#define Cn 256
#define Nh 8
#define Dh 32
#define Fn 1024
#define Ln (Hn*Wn)          // 3136
#define Mrows (Bn*Ln)       // 6272
#define SCALING_K 0.17677669529663687f   // 32^-0.5

typedef __attribute__((ext_vector_type(4))) float f32x4;
typedef __attribute__((ext_vector_type(8))) short s16x8;
typedef unsigned short ushort_t;

__device__ __forceinline__ ushort_t f2bf(float f) {
    __hip_bfloat16 h = __float2bfloat16(f);
    return *reinterpret_cast<ushort_t*>(&h);
}

// async 16B global->LDS copy; LDS dest is wave-uniform base + lane*16 (HW rule)
#define GLOAD16(gp, sp) __builtin_amdgcn_global_load_lds( \
    (const __attribute__((address_space(1))) void*)(gp), \
    (__attribute__((address_space(3))) void*)(sp), 16, 0, 0)

// ---------------- weight transpose: fp32 [K][N] -> bf16 [N][K], LDS-tiled ----------------
__global__ __launch_bounds__(256) void transpose_w(
    const float* __restrict__ wq, const float* __restrict__ wk, const float* __restrict__ wv,
    const float* __restrict__ wo, const float* __restrict__ w1, const float* __restrict__ w2,
    ushort_t* __restrict__ wqkvT, ushort_t* __restrict__ woT,
    ushort_t* __restrict__ w1T, ushort_t* __restrict__ w2T)
{
    int z = blockIdx.z;
    const float* src; ushort_t* dst; int K, N; float scale = 1.f;
    switch (z) {
      case 0: src=wq; dst=wqkvT;           K=256;  N=256;  break;
      case 1: src=wk; dst=wqkvT+256*256;   K=256;  N=256;  scale=SCALING_K; break;
      case 2: src=wv; dst=wqkvT+512*256;   K=256;  N=256;  break;
      case 3: src=wo; dst=woT;             K=256;  N=256;  break;
      case 4: src=w1; dst=w1T;             K=256;  N=1024; break;
      default: src=w2; dst=w2T;            K=1024; N=256;  break;
    }
    int n0 = blockIdx.x << 5, k0 = blockIdx.y << 5;
    if (n0 >= N || k0 >= K) return;
    __shared__ float tile[32][33];
    int tx = threadIdx.x & 31, ty = threadIdx.x >> 5;   // 32 x 8
    #pragma unroll
    for (int r = 0; r < 4; ++r)
        tile[ty + 8*r][tx] = src[(size_t)(k0 + ty + 8*r)*N + n0 + tx] * scale;
    __syncthreads();
    #pragma unroll
    for (int r = 0; r < 4; ++r)
        dst[(size_t)(n0 + ty + 8*r)*K + k0 + tx] = f2bf(tile[tx][ty + 8*r]);
}

__global__ void prep_bias(const float* __restrict__ bq, const float* __restrict__ bk,
                          const float* __restrict__ bv, float* __restrict__ bqkv)
{
    int i = blockIdx.x*256 + threadIdx.x;
    if (i < 768)
        bqkv[i] = (i < 256) ? bq[i] : (i < 512 ? bk[i-256]*SCALING_K : bv[i-512]);
}

// ---------------- pos dwconv3x3 + residual; fused LN1-apply -> bf16 A ----------------
__global__ __launch_bounds__(256) void dwconv_ln(
    const float* __restrict__ x, const float* __restrict__ wgt, const float* __restrict__ bias,
    const float* __restrict__ lng, const float* __restrict__ lnb,
    float* __restrict__ out, ushort_t* __restrict__ ybf)
{
    int t = threadIdx.x;
    int cg = t & 63;
    int g = blockIdx.x*4 + (t >> 6);       // pixel-quad index
    int w0 = (g % 14) << 2;
    int hr = g / 14;                        // b*Hn + h
    int h = hr % Hn;
    int c = cg << 2;
    float4 wv9[9];
    #pragma unroll
    for (int i = 0; i < 9; ++i) wv9[i] = *(const float4*)&wgt[i*Cn + c];
    float4 bias4 = *(const float4*)&bias[c];
    float4 acc[4] = {bias4, bias4, bias4, bias4};
    const float* base = x + (size_t)(hr - h)*Wn*Cn + c;
    #pragma unroll
    for (int dh = 0; dh < 3; ++dh) {
        int hh = h + dh - 1;
        if (hh < 0 || hh >= Hn) continue;
        const float* rowp = base + (size_t)hh*Wn*Cn;
        float4 xv[6];
        #pragma unroll
        for (int j = 0; j < 6; ++j) {
            int wc = w0 - 1 + j;
            xv[j] = (wc >= 0 && wc < Wn) ? *(const float4*)&rowp[(size_t)wc*Cn]
                                         : make_float4(0.f,0.f,0.f,0.f);
        }
        #pragma unroll
        for (int dw = 0; dw < 3; ++dw) {
            float4 wv = wv9[dh*3 + dw];
            #pragma unroll
            for (int p = 0; p < 4; ++p) {
                acc[p].x += xv[p+dw].x*wv.x; acc[p].y += xv[p+dw].y*wv.y;
                acc[p].z += xv[p+dw].z*wv.z; acc[p].w += xv[p+dw].w*wv.w;
            }
        }
        if (dh == 1) {
            #pragma unroll
            for (int p = 0; p < 4; ++p) {
                acc[p].x += xv[p+1].x; acc[p].y += xv[p+1].y;
                acc[p].z += xv[p+1].z; acc[p].w += xv[p+1].w;
            }
        }
    }
    float s[4], q[4];
    #pragma unroll
    for (int p = 0; p < 4; ++p) {
        s[p] = acc[p].x + acc[p].y + acc[p].z + acc[p].w;
        q[p] = acc[p].x*acc[p].x + acc[p].y*acc[p].y + acc[p].z*acc[p].z + acc[p].w*acc[p].w;
    }
    #pragma unroll
    for (int m = 1; m < 64; m <<= 1) {
        #pragma unroll
        for (int p = 0; p < 4; ++p) {
            s[p] += __shfl_xor(s[p], m);
            q[p] += __shfl_xor(q[p], m);
        }
    }
    float4 g4 = *(const float4*)&lng[c];
    float4 b4 = *(const float4*)&lnb[c];
    size_t pixbase = (size_t)hr*Wn + w0;
    #pragma unroll
    for (int p = 0; p < 4; ++p) {
        *(float4*)&out[(pixbase + p)*Cn + c] = acc[p];
        float mean = s[p] * (1.0f/Cn);
        float rstd = rsqrtf(q[p] * (1.0f/Cn) - mean*mean + 1e-6f);
        ushort_t o[4] = {
            f2bf((acc[p].x - mean)*rstd*g4.x + b4.x),
            f2bf((acc[p].y - mean)*rstd*g4.y + b4.y),
            f2bf((acc[p].z - mean)*rstd*g4.z + b4.z),
            f2bf((acc[p].w - mean)*rstd*g4.w + b4.w)
        };
        *(uint2*)&ybf[(pixbase + p)*Cn + c] = *(uint2*)o;
    }
}

// ---------------- generic dwconv, 4 pixels/thread, optional bf16 out ----------------
template<int KS, int OBF>
__global__ __launch_bounds__(256) void dwconv4(
    const float* __restrict__ in, const float* __restrict__ wgt, const float* __restrict__ bias,
    void* __restrict__ outv, int C, int inld, int addin)
{
    constexpr int PAD = KS/2;
    int t = threadIdx.x;
    int cgs = C >> 2;
    int qpb = 256 / cgs;
    int cg = t % cgs;
    int g = blockIdx.x*qpb + t/cgs;
    int w0 = (g % 14) << 2;
    int hr = g / 14;
    int h = hr % Hn;
    int c = cg << 2;
    float4 bias4 = *(const float4*)&bias[c];
    float4 acc[4] = {bias4, bias4, bias4, bias4};
    const float* base = in + (size_t)(hr - h)*Wn*inld + c;
    #pragma unroll
    for (int dh = 0; dh < KS; ++dh) {
        int hh = h + dh - PAD;
        if (hh < 0 || hh >= Hn) continue;
        const float* rowp = base + (size_t)hh*Wn*inld;
        float4 xv[KS+3];
        #pragma unroll
        for (int j = 0; j < KS+3; ++j) {
            int wc = w0 - PAD + j;
            xv[j] = (wc >= 0 && wc < Wn) ? *(const float4*)&rowp[(size_t)wc*inld]
                                         : make_float4(0.f,0.f,0.f,0.f);
        }
        #pragma unroll
        for (int dw = 0; dw < KS; ++dw) {
            float4 wv = *(const float4*)&wgt[(dh*KS + dw)*C + c];
            #pragma unroll
            for (int p = 0; p < 4; ++p) {
                acc[p].x += xv[p+dw].x*wv.x; acc[p].y += xv[p+dw].y*wv.y;
                acc[p].z += xv[p+dw].z*wv.z; acc[p].w += xv[p+dw].w*wv.w;
            }
        }
        if (addin && dh == PAD) {
            #pragma unroll
            for (int p = 0; p < 4; ++p) {
                acc[p].x += xv[p+PAD].x; acc[p].y += xv[p+PAD].y;
                acc[p].z += xv[p+PAD].z; acc[p].w += xv[p+PAD].w;
            }
        }
    }
    size_t pixbase = (size_t)hr*Wn + w0;
    if (OBF) {
        ushort_t* outb = (ushort_t*)outv;
        #pragma unroll
        for (int p = 0; p < 4; ++p) {
            ushort_t tmp[4] = { f2bf(acc[p].x), f2bf(acc[p].y), f2bf(acc[p].z), f2bf(acc[p].w) };
            *(uint2*)&outb[(pixbase + p)*C + c] = *(uint2*)tmp;
        }
    } else {
        float* outf = (float*)outv;
        #pragma unroll
        for (int p = 0; p < 4; ++p)
            *(float4*)&outf[(pixbase + p)*C + c] = acc[p];
    }
}

// ---------------- LN2: stats + apply + bf16 cast, one wave per row ----------------
__global__ __launch_bounds__(256) void ln_apply(
    const float* __restrict__ in, const float* __restrict__ g, const float* __restrict__ b,
    ushort_t* __restrict__ out)
{
    int t = threadIdx.x;
    int lane = t & 63;
    int row = blockIdx.x*4 + (t >> 6);
    int c = lane << 2;
    float4 v = *(const float4*)&in[(size_t)row*Cn + c];
    float s1 = v.x + v.y + v.z + v.w;
    float s2 = v.x*v.x + v.y*v.y + v.z*v.z + v.w*v.w;
    #pragma unroll
    for (int m = 1; m < 64; m <<= 1) {
        s1 += __shfl_xor(s1, m);
        s2 += __shfl_xor(s2, m);
    }
    float mean = s1 * (1.0f/Cn);
    float rstd = rsqrtf(s2 * (1.0f/Cn) - mean*mean + 1e-6f);
    float4 g4 = *(const float4*)&g[c];
    float4 b4 = *(const float4*)&b[c];
    ushort_t o[4] = {
        f2bf((v.x - mean)*rstd*g4.x + b4.x),
        f2bf((v.y - mean)*rstd*g4.y + b4.y),
        f2bf((v.z - mean)*rstd*g4.z + b4.z),
        f2bf((v.w - mean)*rstd*g4.w + b4.w)
    };
    *(uint2*)&out[(size_t)row*Cn + c] = *(uint2*)o;
}

// ---------------- bf16 MFMA GEMM: 64x64 tile, BK=64, global_load_lds + XOR swizzle ----------------
// m97-style staging: linear LDS dest, pre-swizzled global source, swizzled ds_read.
// Swizzle: 16B chunk index ^= (row&7)  (involution; residual 2-way conflict = free).
// 256 thr / 4 waves; per K-step: 4 gload_lds/thread, 2 barriers, 8 MFMA/wave.
__global__ __launch_bounds__(256) void gemm_bf16(
    const ushort_t* __restrict__ A, int lda,
    const ushort_t* __restrict__ BT, const float* __restrict__ bias,
    const float* __restrict__ resid, float* __restrict__ out, int ldo,
    int K, int gelu_flag)
{
    __shared__ __align__(16) ushort_t As[64*64];   // [row][64], 128B rows, chunk-swizzled
    __shared__ __align__(16) ushort_t Bs[64*64];
    int t = threadIdx.x;
    int wid = t >> 6, lane = t & 63, l16 = lane & 15, quad = lane >> 4;
    int n0 = blockIdx.x << 6, m0 = blockIdx.y << 6;
    // staging map: lane l stages 16B chunk (row = base + (l>>3), cchunk = l&7)
    // source chunk pre-swizzled: cchunk ^ (row&7); row&7 == l>>3 here.
    int rl = lane >> 3;                       // 0..7
    int swc = ((lane & 7) ^ rl) << 3;         // source elem offset within row
    const ushort_t* aA = A  + (size_t)(m0 + wid*8 + rl)*lda + swc;
    const ushort_t* aB = BT + (size_t)(n0 + wid*8 + rl)*K   + swc;
    int x7 = l16 & 7;
    f32x4 acc[4] = {{0,0,0,0},{0,0,0,0},{0,0,0,0},{0,0,0,0}};
    for (int k0 = 0; k0 < K; k0 += 64) {
        __syncthreads();                      // prior reads done before overwrite
        GLOAD16(aA + k0,                 &As[wid*512]);
        GLOAD16(aA + k0 + (size_t)32*lda, &As[2048 + wid*512]);
        GLOAD16(aB + k0,                 &Bs[wid*512]);
        GLOAD16(aB + k0 + (size_t)32*K,   &Bs[2048 + wid*512]);
        __syncthreads();                      // vmcnt(0) drained -> tile visible
        #pragma unroll
        for (int kk = 0; kk < 2; ++kk) {
            int ch = (((kk << 2) | quad) ^ x7) << 3;
            s16x8 af = *(const s16x8*)&As[(wid*16 + l16)*64 + ch];
            #pragma unroll
            for (int j = 0; j < 4; ++j) {
                s16x8 bf = *(const s16x8*)&Bs[(j*16 + l16)*64 + ch];
                acc[j] = __builtin_amdgcn_mfma_f32_16x16x32_bf16(af, bf, acc[j], 0, 0, 0);
            }
        }
    }
    #pragma unroll
    for (int j = 0; j < 4; ++j) {
        int col = n0 + j*16 + l16;
        float bv = bias[col];
        #pragma unroll
        for (int r = 0; r < 4; ++r) {
            int row = m0 + wid*16 + quad*4 + r;
            float v = acc[j][r] + bv;
            if (gelu_flag) v = 0.5f * v * (1.0f + erff(v * 0.70710678118654752f));
            size_t off = (size_t)row*ldo + col;
            if (resid) v += resid[off];
            out[off] = v;
        }
    }
}

// ---------------- pack: theta-shift + cast to bf16, head-major; V transposed ----------------
__global__ __launch_bounds__(256) void pack_qkv(
    const float* __restrict__ qkv,
    const float* __restrict__ sp, const float* __restrict__ cp,
    ushort_t* __restrict__ qb, ushort_t* __restrict__ kb, ushort_t* __restrict__ vbT)
{
    __shared__ __align__(16) ushort_t Vl[64][40];
    int t = threadIdx.x;
    int l0 = blockIdx.x << 6;
    int n = blockIdx.y;
    int b = blockIdx.z;
    {
        int ll = t >> 2, dc = (t & 3) << 3;
        int l = l0 + ll;
        size_t gbase = ((size_t)(b*Ln + l))*768 + n*Dh + dc;
        float qx[8], kx[8], vx[8], sv[8], cv[8];
        *(float4*)&qx[0] = *(const float4*)&qkv[gbase];
        *(float4*)&qx[4] = *(const float4*)&qkv[gbase+4];
        *(float4*)&kx[0] = *(const float4*)&qkv[gbase+256];
        *(float4*)&kx[4] = *(const float4*)&qkv[gbase+260];
        *(float4*)&vx[0] = *(const float4*)&qkv[gbase+512];
        *(float4*)&vx[4] = *(const float4*)&qkv[gbase+516];
        size_t scb = (size_t)l*Dh + dc;
        *(float4*)&sv[0] = *(const float4*)&sp[scb];
        *(float4*)&sv[4] = *(const float4*)&sp[scb+4];
        *(float4*)&cv[0] = *(const float4*)&cp[scb];
        *(float4*)&cv[4] = *(const float4*)&cp[scb+4];
        ushort_t qo[8], ko[8], vo[8];
        #pragma unroll
        for (int j = 0; j < 8; j += 2) {
            float q0 = qx[j]*cv[j] - qx[j+1]*sv[j];
            float q1 = qx[j+1]*cv[j+1] + qx[j]*sv[j+1];
            float k0 = kx[j]*cv[j] - kx[j+1]*sv[j];
            float k1 = kx[j+1]*cv[j+1] + kx[j]*sv[j+1];
            qo[j] = f2bf(q0); qo[j+1] = f2bf(q1);
            ko[j] = f2bf(k0); ko[j+1] = f2bf(k1);
            vo[j] = f2bf(vx[j]); vo[j+1] = f2bf(vx[j+1]);
        }
        size_t hbase = ((size_t)((b*Nh + n)*Ln + l))*Dh + dc;
        *(uint4*)&qb[hbase] = *(uint4*)qo;
        *(uint4*)&kb[hbase] = *(uint4*)ko;
        *(uint4*)&Vl[ll][dc] = *(uint4*)vo;
    }
    __syncthreads();
    {
        int d = t >> 3, lc = (t & 7) << 3;
        ushort_t tmp[8];
        #pragma unroll
        for (int i = 0; i < 8; ++i) tmp[i] = Vl[lc + i][d];
        size_t tbase = ((size_t)((b*Nh + n)*Dh + d))*Ln + l0 + lc;
        *(uint4*)&vbT[tbase] = *(uint4*)tmp;
    }
}

// ---------------- MFMA flash attention, batch-merged, register-prefetch pipeline ----------------
// Epilogue fuses +lepe and emits bf16 (the A operand of the wo GEMM).
__global__ __launch_bounds__(512) void flash_mfma(
    const ushort_t* __restrict__ qb, const ushort_t* __restrict__ kb,
    const ushort_t* __restrict__ vbT, const float* __restrict__ mask,
    const float* __restrict__ lepe, ushort_t* __restrict__ out)
{
    __shared__ __align__(16) ushort_t Kt[2][64][40];   // [b][key][d]
    __shared__ __align__(16) ushort_t Vt[2][32][72];   // [b][d][key]
    __shared__ __align__(16) ushort_t Ps[8][16][72];   // per-wave P tile
    int t = threadIdx.x;
    int wid = t >> 6, lane = t & 63, l16 = lane & 15, quad = lane >> 4;
    int bb = wid & 1, wq16 = wid >> 1;
    int l0 = blockIdx.x << 6;
    int n = blockIdx.y;

    const ushort_t* qbp = qb + ((size_t)(bb*Nh + n))*Ln*Dh;
    s16x8 qfrag = *(const s16x8*)(qbp + (size_t)(l0 + wq16*16 + l16)*Dh + quad*8);
    const float* mbase = mask + (size_t)n*Ln*Ln + (size_t)(l0 + wq16*16 + quad*4)*Ln;

    int sb   = t >> 8;
    int krow = (t >> 2) & 63, kkc = (t & 3) << 3;
    int vrow = (t >> 3) & 31, vkc = (t & 7) << 3;
    const ushort_t* kst = kb  + ((size_t)(sb*Nh + n))*Ln*Dh;
    const ushort_t* vst = vbT + ((size_t)((sb*Nh + n)*Dh + vrow))*Ln;

    f32x4 O0 = {0.f,0.f,0.f,0.f}, O1 = {0.f,0.f,0.f,0.f};
    float m_[4], l_[4];
    #pragma unroll
    for (int r = 0; r < 4; ++r) { m_[r] = -INFINITY; l_[r] = 0.f; }

    // prologue prefetch for tile 0
    uint4 kreg = *(const uint4*)(kst + (size_t)krow*Dh + kkc);
    uint4 vreg = *(const uint4*)(vst + vkc);
    f32x4 c0, c1, c2, c3;
    #pragma unroll
    for (int r = 0; r < 4; ++r) {
        const float* mr = mbase + (size_t)r*Ln + l16;
        c0[r] = mr[0]; c1[r] = mr[16]; c2[r] = mr[32]; c3[r] = mr[48];
    }

    for (int m0 = 0; m0 < Ln; m0 += 64) {
        __syncthreads();
        *(uint4*)&Kt[sb][krow][kkc] = kreg;
        *(uint4*)&Vt[sb][vrow][vkc] = vreg;
        __syncthreads();

        // prefetch next tile (in flight across this iteration's compute)
        int m1 = m0 + 64;
        uint4 krn = kreg, vrn = vreg;
        f32x4 d0 = c0, d1 = c1, d2 = c2, d3 = c3;
        if (m1 < Ln) {
            krn = *(const uint4*)(kst + (size_t)(m1 + krow)*Dh + kkc);
            vrn = *(const uint4*)(vst + m1 + vkc);
            #pragma unroll
            for (int r = 0; r < 4; ++r) {
                const float* mr = mbase + (size_t)r*Ln + m1 + l16;
                d0[r] = mr[0]; d1[r] = mr[16]; d2[r] = mr[32]; d3[r] = mr[48];
            }
        }

        f32x4 S[4];
        {
            s16x8 kf0 = *(const s16x8*)&Kt[bb][ 0 + l16][quad*8];
            s16x8 kf1 = *(const s16x8*)&Kt[bb][16 + l16][quad*8];
            s16x8 kf2 = *(const s16x8*)&Kt[bb][32 + l16][quad*8];
            s16x8 kf3 = *(const s16x8*)&Kt[bb][48 + l16][quad*8];
            S[0] = __builtin_amdgcn_mfma_f32_16x16x32_bf16(qfrag, kf0, c0, 0, 0, 0);
            S[1] = __builtin_amdgcn_mfma_f32_16x16x32_bf16(qfrag, kf1, c1, 0, 0, 0);
            S[2] = __builtin_amdgcn_mfma_f32_16x16x32_bf16(qfrag, kf2, c2, 0, 0, 0);
            S[3] = __builtin_amdgcn_mfma_f32_16x16x32_bf16(qfrag, kf3, c3, 0, 0, 0);
        }
        #pragma unroll
        for (int r = 0; r < 4; ++r) {
            float tm = fmaxf(fmaxf(S[0][r], S[1][r]), fmaxf(S[2][r], S[3][r]));
            tm = fmaxf(tm, __shfl_xor(tm, 1));
            tm = fmaxf(tm, __shfl_xor(tm, 2));
            tm = fmaxf(tm, __shfl_xor(tm, 4));
            tm = fmaxf(tm, __shfl_xor(tm, 8));
            float nm = fmaxf(m_[r], tm);
            float al = __expf(m_[r] - nm);
            m_[r] = nm;
            float p0 = __expf(S[0][r] - nm);
            float p1 = __expf(S[1][r] - nm);
            float p2 = __expf(S[2][r] - nm);
            float p3 = __expf(S[3][r] - nm);
            float ps = p0 + p1 + p2 + p3;
            ps += __shfl_xor(ps, 1); ps += __shfl_xor(ps, 2);
            ps += __shfl_xor(ps, 4); ps += __shfl_xor(ps, 8);
            l_[r] = l_[r]*al + ps;
            O0[r] *= al; O1[r] *= al;
            int rr = quad*4 + r;
            Ps[wid][rr][ 0 + l16] = f2bf(p0);
            Ps[wid][rr][16 + l16] = f2bf(p1);
            Ps[wid][rr][32 + l16] = f2bf(p2);
            Ps[wid][rr][48 + l16] = f2bf(p3);
        }
        #pragma unroll
        for (int kc = 0; kc < 2; ++kc) {
            s16x8 pf  = *(const s16x8*)&Ps[wid][l16][kc*32 + quad*8];
            s16x8 vf0 = *(const s16x8*)&Vt[bb][ 0 + l16][kc*32 + quad*8];
            s16x8 vf1 = *(const s16x8*)&Vt[bb][16 + l16][kc*32 + quad*8];
            O0 = __builtin_amdgcn_mfma_f32_16x16x32_bf16(pf, vf0, O0, 0, 0, 0);
            O1 = __builtin_amdgcn_mfma_f32_16x16x32_bf16(pf, vf1, O1, 0, 0, 0);
        }
        kreg = krn; vreg = vrn;
        c0 = d0; c1 = d1; c2 = d2; c3 = d3;
    }
    #pragma unroll
    for (int r = 0; r < 4; ++r) {
        float inv = 1.0f / l_[r];
        size_t row = (size_t)(bb*Ln + l0 + wq16*16 + quad*4 + r)*Cn + n*Dh;
        out[row + l16]      = f2bf(O0[r] * inv + lepe[row + l16]);
        out[row + 16 + l16] = f2bf(O1[r] * inv + lepe[row + 16 + l16]);
    }
}

extern "C" void kernel_launch(void* const* d_in, const int* in_sizes, int n_in,
                              void* d_out, int out_size, void* d_ws, size_t ws_size,
                              hipStream_t stream) {
    const float* x     = (const float*)d_in[0];
    const float* sinp  = (const float*)d_in[1];
    const float* cosp  = (const float*)d_in[2];
    const float* mask  = (const float*)d_in[3];
    const float* pos_w = (const float*)d_in[4];
    const float* pos_b = (const float*)d_in[5];
    const float* ln1_g = (const float*)d_in[6];
    const float* ln1_b = (const float*)d_in[7];
    const float* wq = (const float*)d_in[8];
    const float* bq = (const float*)d_in[9];
    const float* wk = (const float*)d_in[10];
    const float* bk = (const float*)d_in[11];
    const float* wv = (const float*)d_in[12];
    const float* bv = (const float*)d_in[13];
    const float* lepe_w = (const float*)d_in[14];
    const float* lepe_b = (const float*)d_in[15];
    const float* wo = (const float*)d_in[16];
    const float* bo = (const float*)d_in[17];
    const float* ln2_g = (const float*)d_in[18];
    const float* ln2_b = (const float*)d_in[19];
    const float* w1 = (const float*)d_in[20];
    const float* b1 = (const float*)d_in[21];
    const float* ffn_w = (const float*)d_in[22];
    const float* ffn_b = (const float*)d_in[23];
    const float* w2 = (const float*)d_in[24];
    const float* b2 = (const float*)d_in[25];

    float* ws = (float*)d_ws;
    const size_t MC = (size_t)Mrows*Cn;   // 1,605,632 floats
    const size_t HC = MC/2;               // 802,816 floats
    // Compact layout with lifetime-based reuse (peak ~72 MB):
    float* xbuf = ws;
    float* x2   = ws + MC;
    float* lepe = ws + 2*MC;
    ushort_t* ybf   = (ushort_t*)(ws + 3*MC);
    ushort_t* attbf = (ushort_t*)(ws + 3*MC + HC);
    ushort_t* zbf   = (ushort_t*)(ws + 4*MC);
    float* qkv = ws + 4*MC + HC;
    ushort_t* qb  = (ushort_t*)(ws + 7*MC + HC);
    ushort_t* kb  = (ushort_t*)(ws + 8*MC);
    ushort_t* vbT = (ushort_t*)(ws + 8*MC + HC);
    float* z1 = ws + 4*MC + HC;               // reuses qkv/qb/kb region
    ushort_t* z2bf = (ushort_t*)(ws + 9*MC);  // 2MC floats
    float* wtb = ws + 11*MC;
    ushort_t* wqkvT = (ushort_t*)wtb;                 // 196608 us = 98304 f
    ushort_t* woT   = (ushort_t*)(wtb + 98304);       // 65536 us = 32768 f
    ushort_t* w1T   = (ushort_t*)(wtb + 131072);      // 262144 us = 131072 f
    ushort_t* w2T   = (ushort_t*)(wtb + 262144);      // 262144 us = 131072 f
    float*    bqkv  = wtb + 393216;                   // 768 f
    float* outp = (float*)d_out;

    // 0. weight prep
    transpose_w<<<dim3(32,32,6), 256, 0, stream>>>(wq,wk,wv,wo,w1,w2, wqkvT,woT,w1T,w2T);
    prep_bias<<<3, 256, 0, stream>>>(bq,bk,bv,bqkv);
    // 1. xbuf = x + dwconv3x3(x); ybf = bf16(LN1(xbuf)) fused
    dwconv_ln<<<Mrows/16, 256, 0, stream>>>(x, pos_w, pos_b, ln1_g, ln1_b, xbuf, ybf);
    // 2. qkv = ybf @ [wq|wk*s|wv] + [bq|bk*s|bv]
    gemm_bf16<<<dim3(12, Mrows/64), 256, 0, stream>>>(ybf, Cn,
        wqkvT, bqkv, nullptr, qkv, 768, Cn, 0);
    // 3. pack: theta shift + bf16 head-major + V transpose
    pack_qkv<<<dim3(Ln/64, Nh, Bn), 256, 0, stream>>>(qkv, sinp, cosp, qb, kb, vbT);
    // 4. lepe = dwconv5x5(v)
    dwconv4<5,0><<<Mrows/16, 256, 0, stream>>>(qkv+512, lepe_w, lepe_b, lepe, Cn, 768, 0);
    // 5. attention; epilogue adds lepe and emits bf16
    flash_mfma<<<dim3(Ln/64, Nh), 512, 0, stream>>>(qb, kb, vbT, mask, lepe, attbf);
    // 6. x2 = xbuf + attbf @ wo + bo
    gemm_bf16<<<dim3(4, Mrows/64), 256, 0, stream>>>(attbf, Cn,
        woT, bo, xbuf, x2, Cn, Cn, 0);
    // 7. zbf = bf16(LN2(x2))
    ln_apply<<<Mrows/4, 256, 0, stream>>>(x2, ln2_g, ln2_b, zbf);
    // 8. z1 = gelu(zbf @ w1 + b1)
    gemm_bf16<<<dim3(16, Mrows/64), 256, 0, stream>>>(zbf, Cn,
        w1T, b1, nullptr, z1, Fn, Cn, 1);
    // 9. z2 = z1 + dwconv3x3(z1), stored bf16
    dwconv4<3,1><<<Mrows/4, 256, 0, stream>>>(z1, ffn_w, ffn_b, z2bf, Fn, Fn, 1);
    // 10. out = x2 + z2 @ w2 + b2
    gemm_bf16<<<dim3(4, Mrows/64), 256, 0, stream>>>(z2bf, Fn,
        w2T, b2, x2, outp, Cn, Fn, 0);
}

// Round 4
// 603.563 us; speedup vs baseline: 1.0857x; 1.0424x over previous
//
#include <hip/hip_runtime.h>
#include <hip/hip_bf16.h>
#include <math.h>

#define Bn 2
#define Hn 56
#define Wn 56
#define Cn 256
#define Nh 8
#define Dh 32
#define Fn 1024
#define Ln (Hn*Wn)          // 3136
#define Mrows (Bn*Ln)       // 6272
#define SCALING_K 0.17677669529663687f   // 32^-0.5

typedef __attribute__((ext_vector_type(4))) float f32x4;
typedef __attribute__((ext_vector_type(8))) short s16x8;
typedef unsigned short ushort_t;

__device__ __forceinline__ ushort_t f2bf(float f) {
    __hip_bfloat16 h = __float2bfloat16(f);
    return *reinterpret_cast<ushort_t*>(&h);
}

// async 16B global->LDS copy; LDS dest is wave-uniform base + lane*16 (HW rule)
#define GLOAD16(gp, sp) __builtin_amdgcn_global_load_lds( \
    (const __attribute__((address_space(1))) void*)(gp), \
    (__attribute__((address_space(3))) void*)(sp), 16, 0, 0)

// ---------------- weight transpose: fp32 [K][N] -> bf16 [N][K], LDS-tiled; z=6 packs bias ----------------
__global__ __launch_bounds__(256) void transpose_w(
    const float* __restrict__ wq, const float* __restrict__ wk, const float* __restrict__ wv,
    const float* __restrict__ wo, const float* __restrict__ w1, const float* __restrict__ w2,
    const float* __restrict__ bq, const float* __restrict__ bk, const float* __restrict__ bv,
    ushort_t* __restrict__ wqkvT, ushort_t* __restrict__ woT,
    ushort_t* __restrict__ w1T, ushort_t* __restrict__ w2T, float* __restrict__ bqkv)
{
    int z = blockIdx.z;
    if (z == 6) {
        if (blockIdx.x == 0 && blockIdx.y == 0) {
            for (int i = threadIdx.x; i < 768; i += 256)
                bqkv[i] = (i < 256) ? bq[i] : (i < 512 ? bk[i-256]*SCALING_K : bv[i-512]);
        }
        return;
    }
    const float* src; ushort_t* dst; int K, N; float scale = 1.f;
    switch (z) {
      case 0: src=wq; dst=wqkvT;           K=256;  N=256;  break;
      case 1: src=wk; dst=wqkvT+256*256;   K=256;  N=256;  scale=SCALING_K; break;
      case 2: src=wv; dst=wqkvT+512*256;   K=256;  N=256;  break;
      case 3: src=wo; dst=woT;             K=256;  N=256;  break;
      case 4: src=w1; dst=w1T;             K=256;  N=1024; break;
      default: src=w2; dst=w2T;            K=1024; N=256;  break;
    }
    int n0 = blockIdx.x << 5, k0 = blockIdx.y << 5;
    if (n0 >= N || k0 >= K) return;
    __shared__ float tile[32][33];
    int tx = threadIdx.x & 31, ty = threadIdx.x >> 5;   // 32 x 8
    #pragma unroll
    for (int r = 0; r < 4; ++r)
        tile[ty + 8*r][tx] = src[(size_t)(k0 + ty + 8*r)*N + n0 + tx] * scale;
    __syncthreads();
    #pragma unroll
    for (int r = 0; r < 4; ++r)
        dst[(size_t)(n0 + ty + 8*r)*K + k0 + tx] = f2bf(tile[tx][ty + 8*r]);
}

// ---------------- pos dwconv3x3 + residual; fused LN1-apply -> bf16 A ----------------
__global__ __launch_bounds__(256) void dwconv_ln(
    const float* __restrict__ x, const float* __restrict__ wgt, const float* __restrict__ bias,
    const float* __restrict__ lng, const float* __restrict__ lnb,
    float* __restrict__ out, ushort_t* __restrict__ ybf)
{
    int t = threadIdx.x;
    int cg = t & 63;
    int g = blockIdx.x*4 + (t >> 6);       // pixel-quad index
    int w0 = (g % 14) << 2;
    int hr = g / 14;                        // b*Hn + h
    int h = hr % Hn;
    int c = cg << 2;
    float4 wv9[9];
    #pragma unroll
    for (int i = 0; i < 9; ++i) wv9[i] = *(const float4*)&wgt[i*Cn + c];
    float4 bias4 = *(const float4*)&bias[c];
    float4 acc[4] = {bias4, bias4, bias4, bias4};
    const float* base = x + (size_t)(hr - h)*Wn*Cn + c;
    #pragma unroll
    for (int dh = 0; dh < 3; ++dh) {
        int hh = h + dh - 1;
        if (hh < 0 || hh >= Hn) continue;
        const float* rowp = base + (size_t)hh*Wn*Cn;
        float4 xv[6];
        #pragma unroll
        for (int j = 0; j < 6; ++j) {
            int wc = w0 - 1 + j;
            xv[j] = (wc >= 0 && wc < Wn) ? *(const float4*)&rowp[(size_t)wc*Cn]
                                         : make_float4(0.f,0.f,0.f,0.f);
        }
        #pragma unroll
        for (int dw = 0; dw < 3; ++dw) {
            float4 wv = wv9[dh*3 + dw];
            #pragma unroll
            for (int p = 0; p < 4; ++p) {
                acc[p].x += xv[p+dw].x*wv.x; acc[p].y += xv[p+dw].y*wv.y;
                acc[p].z += xv[p+dw].z*wv.z; acc[p].w += xv[p+dw].w*wv.w;
            }
        }
        if (dh == 1) {
            #pragma unroll
            for (int p = 0; p < 4; ++p) {
                acc[p].x += xv[p+1].x; acc[p].y += xv[p+1].y;
                acc[p].z += xv[p+1].z; acc[p].w += xv[p+1].w;
            }
        }
    }
    float s[4], q[4];
    #pragma unroll
    for (int p = 0; p < 4; ++p) {
        s[p] = acc[p].x + acc[p].y + acc[p].z + acc[p].w;
        q[p] = acc[p].x*acc[p].x + acc[p].y*acc[p].y + acc[p].z*acc[p].z + acc[p].w*acc[p].w;
    }
    #pragma unroll
    for (int m = 1; m < 64; m <<= 1) {
        #pragma unroll
        for (int p = 0; p < 4; ++p) {
            s[p] += __shfl_xor(s[p], m);
            q[p] += __shfl_xor(q[p], m);
        }
    }
    float4 g4 = *(const float4*)&lng[c];
    float4 b4 = *(const float4*)&lnb[c];
    size_t pixbase = (size_t)hr*Wn + w0;
    #pragma unroll
    for (int p = 0; p < 4; ++p) {
        *(float4*)&out[(pixbase + p)*Cn + c] = acc[p];
        float mean = s[p] * (1.0f/Cn);
        float rstd = rsqrtf(q[p] * (1.0f/Cn) - mean*mean + 1e-6f);
        ushort_t o[4] = {
            f2bf((acc[p].x - mean)*rstd*g4.x + b4.x),
            f2bf((acc[p].y - mean)*rstd*g4.y + b4.y),
            f2bf((acc[p].z - mean)*rstd*g4.z + b4.z),
            f2bf((acc[p].w - mean)*rstd*g4.w + b4.w)
        };
        *(uint2*)&ybf[(pixbase + p)*Cn + c] = *(uint2*)o;
    }
}

// ---------------- generic dwconv, 4 pixels/thread, optional bf16 out ----------------
template<int KS, int OBF>
__global__ __launch_bounds__(256) void dwconv4(
    const float* __restrict__ in, const float* __restrict__ wgt, const float* __restrict__ bias,
    void* __restrict__ outv, int C, int inld, int addin)
{
    constexpr int PAD = KS/2;
    int t = threadIdx.x;
    int cgs = C >> 2;
    int qpb = 256 / cgs;
    int cg = t % cgs;
    int g = blockIdx.x*qpb + t/cgs;
    int w0 = (g % 14) << 2;
    int hr = g / 14;
    int h = hr % Hn;
    int c = cg << 2;
    float4 bias4 = *(const float4*)&bias[c];
    float4 acc[4] = {bias4, bias4, bias4, bias4};
    const float* base = in + (size_t)(hr - h)*Wn*inld + c;
    #pragma unroll
    for (int dh = 0; dh < KS; ++dh) {
        int hh = h + dh - PAD;
        if (hh < 0 || hh >= Hn) continue;
        const float* rowp = base + (size_t)hh*Wn*inld;
        float4 xv[KS+3];
        #pragma unroll
        for (int j = 0; j < KS+3; ++j) {
            int wc = w0 - PAD + j;
            xv[j] = (wc >= 0 && wc < Wn) ? *(const float4*)&rowp[(size_t)wc*inld]
                                         : make_float4(0.f,0.f,0.f,0.f);
        }
        #pragma unroll
        for (int dw = 0; dw < KS; ++dw) {
            float4 wv = *(const float4*)&wgt[(dh*KS + dw)*C + c];
            #pragma unroll
            for (int p = 0; p < 4; ++p) {
                acc[p].x += xv[p+dw].x*wv.x; acc[p].y += xv[p+dw].y*wv.y;
                acc[p].z += xv[p+dw].z*wv.z; acc[p].w += xv[p+dw].w*wv.w;
            }
        }
        if (addin && dh == PAD) {
            #pragma unroll
            for (int p = 0; p < 4; ++p) {
                acc[p].x += xv[p+PAD].x; acc[p].y += xv[p+PAD].y;
                acc[p].z += xv[p+PAD].z; acc[p].w += xv[p+PAD].w;
            }
        }
    }
    size_t pixbase = (size_t)hr*Wn + w0;
    if (OBF) {
        ushort_t* outb = (ushort_t*)outv;
        #pragma unroll
        for (int p = 0; p < 4; ++p) {
            ushort_t tmp[4] = { f2bf(acc[p].x), f2bf(acc[p].y), f2bf(acc[p].z), f2bf(acc[p].w) };
            *(uint2*)&outb[(pixbase + p)*C + c] = *(uint2*)tmp;
        }
    } else {
        float* outf = (float*)outv;
        #pragma unroll
        for (int p = 0; p < 4; ++p)
            *(float4*)&outf[(pixbase + p)*C + c] = acc[p];
    }
}

// ---------------- LN2: stats + apply + bf16 cast, one wave per row ----------------
__global__ __launch_bounds__(256) void ln_apply(
    const float* __restrict__ in, const float* __restrict__ g, const float* __restrict__ b,
    ushort_t* __restrict__ out)
{
    int t = threadIdx.x;
    int lane = t & 63;
    int row = blockIdx.x*4 + (t >> 6);
    int c = lane << 2;
    float4 v = *(const float4*)&in[(size_t)row*Cn + c];
    float s1 = v.x + v.y + v.z + v.w;
    float s2 = v.x*v.x + v.y*v.y + v.z*v.z + v.w*v.w;
    #pragma unroll
    for (int m = 1; m < 64; m <<= 1) {
        s1 += __shfl_xor(s1, m);
        s2 += __shfl_xor(s2, m);
    }
    float mean = s1 * (1.0f/Cn);
    float rstd = rsqrtf(s2 * (1.0f/Cn) - mean*mean + 1e-6f);
    float4 g4 = *(const float4*)&g[c];
    float4 b4 = *(const float4*)&b[c];
    ushort_t o[4] = {
        f2bf((v.x - mean)*rstd*g4.x + b4.x),
        f2bf((v.y - mean)*rstd*g4.y + b4.y),
        f2bf((v.z - mean)*rstd*g4.z + b4.z),
        f2bf((v.w - mean)*rstd*g4.w + b4.w)
    };
    *(uint2*)&out[(size_t)row*Cn + c] = *(uint2*)o;
}

// ---------------- bf16 MFMA GEMM: 64x64 tile, BK=64, global_load_lds + XOR swizzle ----------------
// epi: 0 = bias(+resid) fp32 out; 1 = bias+gelu fp32 out; 2 = QKV pack epilogue
//   (cols<512: theta-shift in-register via shfl_xor partner, write qb/kb bf16 head-major;
//    cols>=512: write v fp32 [M][256])
__global__ __launch_bounds__(256) void gemm_bf16(
    const ushort_t* __restrict__ A, int lda,
    const ushort_t* __restrict__ BT, const float* __restrict__ bias,
    const float* __restrict__ resid, float* __restrict__ out, int ldo,
    int K, int epi,
    ushort_t* __restrict__ qbo, ushort_t* __restrict__ kbo, float* __restrict__ vbo,
    const float* __restrict__ sp, const float* __restrict__ cp)
{
    __shared__ __align__(16) ushort_t As[64*64];   // [row][64], 128B rows, chunk-swizzled
    __shared__ __align__(16) ushort_t Bs[64*64];
    int t = threadIdx.x;
    int wid = t >> 6, lane = t & 63, l16 = lane & 15, quad = lane >> 4;
    int n0 = blockIdx.x << 6, m0 = blockIdx.y << 6;
    int rl = lane >> 3;                       // 0..7
    int swc = ((lane & 7) ^ rl) << 3;         // pre-swizzled source chunk
    const ushort_t* aA = A  + (size_t)(m0 + wid*8 + rl)*lda + swc;
    const ushort_t* aB = BT + (size_t)(n0 + wid*8 + rl)*K   + swc;
    int x7 = l16 & 7;
    f32x4 acc[4] = {{0,0,0,0},{0,0,0,0},{0,0,0,0},{0,0,0,0}};
    for (int k0 = 0; k0 < K; k0 += 64) {
        __syncthreads();
        GLOAD16(aA + k0,                 &As[wid*512]);
        GLOAD16(aA + k0 + (size_t)32*lda, &As[2048 + wid*512]);
        GLOAD16(aB + k0,                 &Bs[wid*512]);
        GLOAD16(aB + k0 + (size_t)32*K,   &Bs[2048 + wid*512]);
        __syncthreads();
        #pragma unroll
        for (int kk = 0; kk < 2; ++kk) {
            int ch = (((kk << 2) | quad) ^ x7) << 3;
            s16x8 af = *(const s16x8*)&As[(wid*16 + l16)*64 + ch];
            #pragma unroll
            for (int j = 0; j < 4; ++j) {
                s16x8 bf = *(const s16x8*)&Bs[(j*16 + l16)*64 + ch];
                acc[j] = __builtin_amdgcn_mfma_f32_16x16x32_bf16(af, bf, acc[j], 0, 0, 0);
            }
        }
    }
    if (epi == 2) {
        #pragma unroll
        for (int j = 0; j < 4; ++j) {
            int col = n0 + j*16 + l16;
            float bv = bias[col];
            if (col < 512) {               // uniform per j (block n0 aligned to 64)
                int d = col & 31;
                int hn = (col >> 5) & 7;
                ushort_t* dst = (col < 256) ? qbo : kbo;
                #pragma unroll
                for (int r = 0; r < 4; ++r) {
                    int row = m0 + wid*16 + quad*4 + r;
                    float v = acc[j][r] + bv;
                    float vp = __shfl_xor(v, 1);       // partner column value
                    int b = (row >= Ln) ? 1 : 0;
                    int ll = row - b*Ln;
                    float cc = cp[ll*Dh + d];
                    float ss = sp[ll*Dh + d];
                    float o = (col & 1) ? (v*cc + vp*ss) : (v*cc - vp*ss);
                    dst[(((size_t)(b*Nh + hn)*Ln + ll) << 5) + d] = f2bf(o);
                }
            } else {
                #pragma unroll
                for (int r = 0; r < 4; ++r) {
                    int row = m0 + wid*16 + quad*4 + r;
                    vbo[(size_t)row*Cn + (col - 512)] = acc[j][r] + bv;
                }
            }
        }
        return;
    }
    #pragma unroll
    for (int j = 0; j < 4; ++j) {
        int col = n0 + j*16 + l16;
        float bv = bias[col];
        #pragma unroll
        for (int r = 0; r < 4; ++r) {
            int row = m0 + wid*16 + quad*4 + r;
            float v = acc[j][r] + bv;
            if (epi == 1) v = 0.5f * v * (1.0f + erff(v * 0.70710678118654752f));
            size_t off = (size_t)row*ldo + col;
            if (resid) v += resid[off];
            out[off] = v;
        }
    }
}

// ---------------- vpack: v fp32 [M][256] -> bf16 transposed [b,n,d][l] ----------------
__global__ __launch_bounds__(256) void vpack(
    const float* __restrict__ vbuf, ushort_t* __restrict__ vbT)
{
    __shared__ __align__(16) ushort_t Vl[64][40];
    int t = threadIdx.x;
    int l0 = blockIdx.x << 6;
    int n = blockIdx.y;
    int b = blockIdx.z;
    {
        int ll = t >> 2, dc = (t & 3) << 3;
        size_t gbase = ((size_t)(b*Ln + l0 + ll))*Cn + n*Dh + dc;
        float vx[8];
        *(float4*)&vx[0] = *(const float4*)&vbuf[gbase];
        *(float4*)&vx[4] = *(const float4*)&vbuf[gbase+4];
        ushort_t vo[8];
        #pragma unroll
        for (int j = 0; j < 8; ++j) vo[j] = f2bf(vx[j]);
        *(uint4*)&Vl[ll][dc] = *(uint4*)vo;
    }
    __syncthreads();
    {
        int d = t >> 3, lc = (t & 7) << 3;
        ushort_t tmp[8];
        #pragma unroll
        for (int i = 0; i < 8; ++i) tmp[i] = Vl[lc + i][d];
        size_t tbase = ((size_t)((b*Nh + n)*Dh + d))*Ln + l0 + lc;
        *(uint4*)&vbT[tbase] = *(uint4*)tmp;
    }
}

// ---------------- MFMA flash attention, batch-merged, register-prefetch pipeline ----------------
// Epilogue fuses +lepe and emits bf16. l-sum reduction deferred to epilogue.
__global__ __launch_bounds__(512) void flash_mfma(
    const ushort_t* __restrict__ qb, const ushort_t* __restrict__ kb,
    const ushort_t* __restrict__ vbT, const float* __restrict__ mask,
    const float* __restrict__ lepe, ushort_t* __restrict__ out)
{
    __shared__ __align__(16) ushort_t Kt[2][64][40];   // [b][key][d]
    __shared__ __align__(16) ushort_t Vt[2][32][72];   // [b][d][key]
    __shared__ __align__(16) ushort_t Ps[8][16][72];   // per-wave P tile
    int t = threadIdx.x;
    int wid = t >> 6, lane = t & 63, l16 = lane & 15, quad = lane >> 4;
    int bb = wid & 1, wq16 = wid >> 1;
    int l0 = blockIdx.x << 6;
    int n = blockIdx.y;

    const ushort_t* qbp = qb + ((size_t)(bb*Nh + n))*Ln*Dh;
    s16x8 qfrag = *(const s16x8*)(qbp + (size_t)(l0 + wq16*16 + l16)*Dh + quad*8);
    const float* mbase = mask + (size_t)n*Ln*Ln + (size_t)(l0 + wq16*16 + quad*4)*Ln;

    int sb   = t >> 8;
    int krow = (t >> 2) & 63, kkc = (t & 3) << 3;
    int vrow = (t >> 3) & 31, vkc = (t & 7) << 3;
    const ushort_t* kst = kb  + ((size_t)(sb*Nh + n))*Ln*Dh;
    const ushort_t* vst = vbT + ((size_t)((sb*Nh + n)*Dh + vrow))*Ln;

    f32x4 O0 = {0.f,0.f,0.f,0.f}, O1 = {0.f,0.f,0.f,0.f};
    float m_[4], l_[4];
    #pragma unroll
    for (int r = 0; r < 4; ++r) { m_[r] = -INFINITY; l_[r] = 0.f; }

    // prologue prefetch for tile 0
    uint4 kreg = *(const uint4*)(kst + (size_t)krow*Dh + kkc);
    uint4 vreg = *(const uint4*)(vst + vkc);
    f32x4 c0, c1, c2, c3;
    #pragma unroll
    for (int r = 0; r < 4; ++r) {
        const float* mr = mbase + (size_t)r*Ln + l16;
        c0[r] = mr[0]; c1[r] = mr[16]; c2[r] = mr[32]; c3[r] = mr[48];
    }

    for (int m0 = 0; m0 < Ln; m0 += 64) {
        __syncthreads();
        *(uint4*)&Kt[sb][krow][kkc] = kreg;
        *(uint4*)&Vt[sb][vrow][vkc] = vreg;
        __syncthreads();

        // prefetch next tile (in flight across this iteration's compute)
        int m1 = m0 + 64;
        uint4 krn = kreg, vrn = vreg;
        f32x4 d0 = c0, d1 = c1, d2 = c2, d3 = c3;
        if (m1 < Ln) {
            krn = *(const uint4*)(kst + (size_t)(m1 + krow)*Dh + kkc);
            vrn = *(const uint4*)(vst + m1 + vkc);
            #pragma unroll
            for (int r = 0; r < 4; ++r) {
                const float* mr = mbase + (size_t)r*Ln + m1 + l16;
                d0[r] = mr[0]; d1[r] = mr[16]; d2[r] = mr[32]; d3[r] = mr[48];
            }
        }

        f32x4 S[4];
        {
            s16x8 kf0 = *(const s16x8*)&Kt[bb][ 0 + l16][quad*8];
            s16x8 kf1 = *(const s16x8*)&Kt[bb][16 + l16][quad*8];
            s16x8 kf2 = *(const s16x8*)&Kt[bb][32 + l16][quad*8];
            s16x8 kf3 = *(const s16x8*)&Kt[bb][48 + l16][quad*8];
            S[0] = __builtin_amdgcn_mfma_f32_16x16x32_bf16(qfrag, kf0, c0, 0, 0, 0);
            S[1] = __builtin_amdgcn_mfma_f32_16x16x32_bf16(qfrag, kf1, c1, 0, 0, 0);
            S[2] = __builtin_amdgcn_mfma_f32_16x16x32_bf16(qfrag, kf2, c2, 0, 0, 0);
            S[3] = __builtin_amdgcn_mfma_f32_16x16x32_bf16(qfrag, kf3, c3, 0, 0, 0);
        }
        #pragma unroll
        for (int r = 0; r < 4; ++r) {
            float tm = fmaxf(fmaxf(S[0][r], S[1][r]), fmaxf(S[2][r], S[3][r]));
            tm = fmaxf(tm, __shfl_xor(tm, 1));
            tm = fmaxf(tm, __shfl_xor(tm, 2));
            tm = fmaxf(tm, __shfl_xor(tm, 4));
            tm = fmaxf(tm, __shfl_xor(tm, 8));
            float nm = fmaxf(m_[r], tm);
            float al = __expf(m_[r] - nm);
            m_[r] = nm;
            float p0 = __expf(S[0][r] - nm);
            float p1 = __expf(S[1][r] - nm);
            float p2 = __expf(S[2][r] - nm);
            float p3 = __expf(S[3][r] - nm);
            // deferred: keep lane-local partial sum; cross-lane reduce once at epilogue
            l_[r] = l_[r]*al + (p0 + p1 + p2 + p3);
            O0[r] *= al; O1[r] *= al;
            int rr = quad*4 + r;
            Ps[wid][rr][ 0 + l16] = f2bf(p0);
            Ps[wid][rr][16 + l16] = f2bf(p1);
            Ps[wid][rr][32 + l16] = f2bf(p2);
            Ps[wid][rr][48 + l16] = f2bf(p3);
        }
        #pragma unroll
        for (int kc = 0; kc < 2; ++kc) {
            s16x8 pf  = *(const s16x8*)&Ps[wid][l16][kc*32 + quad*8];
            s16x8 vf0 = *(const s16x8*)&Vt[bb][ 0 + l16][kc*32 + quad*8];
            s16x8 vf1 = *(const s16x8*)&Vt[bb][16 + l16][kc*32 + quad*8];
            O0 = __builtin_amdgcn_mfma_f32_16x16x32_bf16(pf, vf0, O0, 0, 0, 0);
            O1 = __builtin_amdgcn_mfma_f32_16x16x32_bf16(pf, vf1, O1, 0, 0, 0);
        }
        kreg = krn; vreg = vrn;
        c0 = d0; c1 = d1; c2 = d2; c3 = d3;
    }
    #pragma unroll
    for (int r = 0; r < 4; ++r) {
        float ls = l_[r];
        ls += __shfl_xor(ls, 1); ls += __shfl_xor(ls, 2);
        ls += __shfl_xor(ls, 4); ls += __shfl_xor(ls, 8);
        float inv = 1.0f / ls;
        size_t row = (size_t)(bb*Ln + l0 + wq16*16 + quad*4 + r)*Cn + n*Dh;
        out[row + l16]      = f2bf(O0[r] * inv + lepe[row + l16]);
        out[row + 16 + l16] = f2bf(O1[r] * inv + lepe[row + 16 + l16]);
    }
}

extern "C" void kernel_launch(void* const* d_in, const int* in_sizes, int n_in,
                              void* d_out, int out_size, void* d_ws, size_t ws_size,
                              hipStream_t stream) {
    const float* x     = (const float*)d_in[0];
    const float* sinp  = (const float*)d_in[1];
    const float* cosp  = (const float*)d_in[2];
    const float* mask  = (const float*)d_in[3];
    const float* pos_w = (const float*)d_in[4];
    const float* pos_b = (const float*)d_in[5];
    const float* ln1_g = (const float*)d_in[6];
    const float* ln1_b = (const float*)d_in[7];
    const float* wq = (const float*)d_in[8];
    const float* bq = (const float*)d_in[9];
    const float* wk = (const float*)d_in[10];
    const float* bk = (const float*)d_in[11];
    const float* wv = (const float*)d_in[12];
    const float* bv = (const float*)d_in[13];
    const float* lepe_w = (const float*)d_in[14];
    const float* lepe_b = (const float*)d_in[15];
    const float* wo = (const float*)d_in[16];
    const float* bo = (const float*)d_in[17];
    const float* ln2_g = (const float*)d_in[18];
    const float* ln2_b = (const float*)d_in[19];
    const float* w1 = (const float*)d_in[20];
    const float* b1 = (const float*)d_in[21];
    const float* ffn_w = (const float*)d_in[22];
    const float* ffn_b = (const float*)d_in[23];
    const float* w2 = (const float*)d_in[24];
    const float* b2 = (const float*)d_in[25];

    float* ws = (float*)d_ws;
    const size_t MC = (size_t)Mrows*Cn;   // 1,605,632 floats
    const size_t HC = MC/2;
    // Lifetime-compacted layout (peak ~69 MB):
    //  [0,1)xbuf  [1,2)x2  [2,3)lepe  [3,3.5)ybf  [3.5,4)attbf  [4,4.5)zbf
    //  [4.5,5.5)vbuf  [5.5,6)qb  [6,6.5)kb  [6.5,7)vbT   (all dead after flash)
    //  z1 reuses [4.5,8.5); z2bf [8.5,10.5); weights at 10.5MC
    float* xbuf = ws;
    float* x2   = ws + MC;
    float* lepe = ws + 2*MC;
    ushort_t* ybf   = (ushort_t*)(ws + 3*MC);
    ushort_t* attbf = (ushort_t*)(ws + 3*MC + HC);
    ushort_t* zbf   = (ushort_t*)(ws + 4*MC);
    float* vbuf = ws + 4*MC + HC;
    ushort_t* qb  = (ushort_t*)(ws + 5*MC + HC);
    ushort_t* kb  = (ushort_t*)(ws + 6*MC);
    ushort_t* vbT = (ushort_t*)(ws + 6*MC + HC);
    float* z1 = ws + 4*MC + HC;               // reuses vbuf/qb/kb/vbT region
    ushort_t* z2bf = (ushort_t*)(ws + 8*MC + HC);
    float* wtb = ws + 10*MC + HC;
    ushort_t* wqkvT = (ushort_t*)wtb;                 // 196608 us = 98304 f
    ushort_t* woT   = (ushort_t*)(wtb + 98304);       // 65536 us = 32768 f
    ushort_t* w1T   = (ushort_t*)(wtb + 131072);      // 262144 us = 131072 f
    ushort_t* w2T   = (ushort_t*)(wtb + 262144);      // 262144 us = 131072 f
    float*    bqkv  = wtb + 393216;                   // 768 f
    float* outp = (float*)d_out;

    // 0. weight prep (+ bias pack, z=6)
    transpose_w<<<dim3(32,32,7), 256, 0, stream>>>(wq,wk,wv,wo,w1,w2, bq,bk,bv,
        wqkvT,woT,w1T,w2T, bqkv);
    // 1. xbuf = x + dwconv3x3(x); ybf = bf16(LN1(xbuf)) fused
    dwconv_ln<<<Mrows/16, 256, 0, stream>>>(x, pos_w, pos_b, ln1_g, ln1_b, xbuf, ybf);
    // 2. QKV GEMM, epilogue packs q/k (theta-shift, bf16 head-major) and v (fp32)
    gemm_bf16<<<dim3(12, Mrows/64), 256, 0, stream>>>(ybf, Cn,
        wqkvT, bqkv, nullptr, nullptr, 0, Cn, 2, qb, kb, vbuf, sinp, cosp);
    // 3. vbT = transpose(bf16(v))
    vpack<<<dim3(Ln/64, Nh, Bn), 256, 0, stream>>>(vbuf, vbT);
    // 4. lepe = dwconv5x5(v)
    dwconv4<5,0><<<Mrows/16, 256, 0, stream>>>(vbuf, lepe_w, lepe_b, lepe, Cn, Cn, 0);
    // 5. attention; epilogue adds lepe and emits bf16
    flash_mfma<<<dim3(Ln/64, Nh), 512, 0, stream>>>(qb, kb, vbT, mask, lepe, attbf);
    // 6. x2 = xbuf + attbf @ wo + bo
    gemm_bf16<<<dim3(4, Mrows/64), 256, 0, stream>>>(attbf, Cn,
        woT, bo, xbuf, x2, Cn, Cn, 0, nullptr, nullptr, nullptr, nullptr, nullptr);
    // 7. zbf = bf16(LN2(x2))
    ln_apply<<<Mrows/4, 256, 0, stream>>>(x2, ln2_g, ln2_b, zbf);
    // 8. z1 = gelu(zbf @ w1 + b1)
    gemm_bf16<<<dim3(16, Mrows/64), 256, 0, stream>>>(zbf, Cn,
        w1T, b1, nullptr, z1, Fn, Cn, 1, nullptr, nullptr, nullptr, nullptr, nullptr);
    // 9. z2 = z1 + dwconv3x3(z1), stored bf16
    dwconv4<3,1><<<Mrows/4, 256, 0, stream>>>(z1, ffn_w, ffn_b, z2bf, Fn, Fn, 1);
    // 10. out = x2 + z2 @ w2 + b2
    gemm_bf16<<<dim3(4, Mrows/64), 256, 0, stream>>>(z2bf, Fn,
        w2T, b2, x2, outp, Cn, Fn, 0, nullptr, nullptr, nullptr, nullptr, nullptr);
}